// Round 8
// baseline (2254.207 us; speedup 1.0000x reference)
//
#include <hip/hip_runtime.h>
#include <stdint.h>

#define B_ 4
#define N_ 256
#define H_ 192
#define H3_ 576
#define F_ 64
#define NBLK 6          // blocks per batch
#define OWNE 32         // own S elements per block
#define OWNC 96         // own W_hh gate cols per block (3*OWNE)

// ---- workspace layout (32-bit words) ----
#define H0_OFF   0u
#define ZC_OFF   1024u
#define GZ_OFF   2048u       // [b][576] z@W_hh + b_hh
#define SG_OFF   4608u       // [b][256][192] S (plain f32)
#define HPG_OFF  201216u     // [b][256][192] h_prov (plain f32)
#define AN_OFF   397824u     // [b][256][4] u64 ancestor masks
#define TG_OFF   406016u     // [b][256][4] u64 target masks
#define PL_OFF   414208u     // parent lists (u8)
#define PC_OFF   479744u     // parent counts
#define DG_OFF   480768u     // 1/deg (unused by pass1 now; kept)
#define D_OFF    481792u     // d-history [b][blk][node][96] f32 (own cols of dfull)
#define G_OFF    1071616u    // G^T [b][k][N]
#define C_OFF    1268224u    // Hprov@W1a + zc
#define FDP_OFF  1464832u    // fast d-partial slots [b][blk][par][576] u64
#define MDP_OFF  1520128u    // MALL d-partial slots (same shape)

#define AN64 (AN_OFF/2)
#define TG64 (TG_OFF/2)
#define FDP64 (FDP_OFF/2)
#define MDP64 (MDP_OFF/2)
#define MOFF64 ((MDP_OFF-FDP_OFF)/2)   // 27648 u64

#define NF_OUT 262144u
#define LL_OUT 327680u

// ---- dynamic LDS word layout (f32 words) ----
#define L_WIH   0u            // [32][577]
#define L_WHH   18464u        // [192][97]
#define L_Q     37088u        // [576]
#define L_GZ    37664u        // [576]
#define L_BIH   38240u        // [576]
#define L_HP    38816u        // [192]
#define L_ZF    39008u        // [192]
#define L_DOWN  39200u        // [96]
#define L_YGA   39296u        // [96]
#define L_GAA   39392u        // [96]
#define L_BHH   39488u        // [96]
#define L_SSO   39584u        // [32]
#define L_SPC   39616u        // [256] u32
#define L_STF   39872u        // [1]
#define SMEM_WORDS 39880u
#define SMEM_BYTES (SMEM_WORDS*4u)

__device__ __forceinline__ float sigm_(float x){ return 1.0f/(1.0f + __expf(-x)); }
__device__ __forceinline__ float tanh_(float x){
  float ax = fabsf(x);
  float e = __expf(-2.0f*ax);
  float t = (1.0f - e)/(1.0f + e);
  return x < 0.0f ? -t : t;
}

__device__ __forceinline__ void st_mall_(unsigned long long* p, unsigned long long u){
  __hip_atomic_store(p, u, __ATOMIC_RELAXED, __HIP_MEMORY_SCOPE_AGENT);
}
__device__ __forceinline__ unsigned long long ld_mall_(const unsigned long long* p){
  return __hip_atomic_load(p, __ATOMIC_RELAXED, __HIP_MEMORY_SCOPE_AGENT);
}
__device__ __forceinline__ void st_fast_(unsigned long long* p, unsigned long long u){
  __hip_atomic_store(p, u, __ATOMIC_RELAXED, __HIP_MEMORY_SCOPE_WORKGROUP);
}
// batched 5-wide nt load: ONE vmcnt wait per poll iteration (not per item).
__device__ __forceinline__ void ld_nt5_(const unsigned long long* p0, const unsigned long long* p1,
    const unsigned long long* p2, const unsigned long long* p3, const unsigned long long* p4,
    unsigned long long& x0, unsigned long long& x1, unsigned long long& x2,
    unsigned long long& x3, unsigned long long& x4){
  asm volatile(
    "global_load_dwordx2 %0, %5, off nt\n\t"
    "global_load_dwordx2 %1, %6, off nt\n\t"
    "global_load_dwordx2 %2, %7, off nt\n\t"
    "global_load_dwordx2 %3, %8, off nt\n\t"
    "global_load_dwordx2 %4, %9, off nt\n\t"
    "s_waitcnt vmcnt(0)"
    : "=&v"(x0),"=&v"(x1),"=&v"(x2),"=&v"(x3),"=&v"(x4)
    : "v"(p0),"v"(p1),"v"(p2),"v"(p3),"v"(p4)
    : "memory");
}
// raw barrier: LDS ordering only (no vmcnt drain).
__device__ __forceinline__ void bar_(){
  asm volatile("s_waitcnt lgkmcnt(0)" ::: "memory");
  __builtin_amdgcn_s_barrier();
  asm volatile("" ::: "memory");
}

// ---------- pre1: (bx<N_): parent lists/bitmasks/deg | (bx==N_): h0, zc, GZ, ll=0 ----------
__global__ void __launch_bounds__(192) k_pre1(const float* __restrict__ z,
    const float* __restrict__ Winit, const float* __restrict__ binit,
    const float* __restrict__ W1, const float* __restrict__ b1,
    const float* __restrict__ Whh, const float* __restrict__ bhh,
    const float* __restrict__ tgt, float* ws, float* out)
{
  int bx = blockIdx.x, b = blockIdx.y, tid = threadIdx.x;
  if (bx == N_){
    __shared__ float zs[H_];
    zs[tid] = z[b*H_ + tid];
    __syncthreads();
    float a0=0.f, a1=0.f;
    for (int k=0;k<H_;k++){
      float zv = zs[k];
      a0 += zv * Winit[(size_t)k*H_ + tid];
      a1 += zv * W1[(size_t)(2*H_ + k)*H_ + tid];
    }
    ws[H0_OFF + b*H_ + tid] = tanh_(a0 + binit[tid]);
    ws[ZC_OFF + b*H_ + tid] = a1 + b1[tid];
    // GZ = z@W_hh + b_hh, all 576 cols (3 per thread)
    #pragma unroll
    for (int g=0; g<3; g++){
      int c = g*H_ + tid;
      float a = 0.f;
      for (int k=0;k<H_;k++) a += zs[k]*Whh[(size_t)k*H3_ + c];
      ws[GZ_OFF + b*H3_ + c] = a + bhh[c];
    }
    if (b==0 && tid==0) out[LL_OUT] = 0.0f;
    return;
  }
  if (tid >= 64) return;
  int t = bx, lane = tid;
  uint32_t* wsu = (uint32_t*)ws;
  unsigned long long* ws64 = (unsigned long long*)ws;
  const float* row = tgt + ((size_t)(b*N_) + t)*N_;
  uint8_t* pl = ((uint8_t*)&wsu[PL_OFF]) + (size_t)(b*N_ + t)*N_;
  int cnt = 0;
  #pragma unroll
  for (int m=0;m<4;m++){
    float v = row[m*64 + lane];
    bool p = (v != 0.0f);
    unsigned long long bw = __ballot(p);
    if (lane == 0) ws64[TG64 + (size_t)(b*N_+t)*4 + m] = bw;
    if (p){
      int pos = cnt + (int)__popcll(bw & ((1ULL<<lane)-1ULL));
      pl[pos] = (uint8_t)(m*64 + lane);
    }
    cnt += (int)__popcll(bw);
  }
  if (lane == 0){
    wsu[PC_OFF + b*N_ + t] = (uint32_t)cnt;
    ws[DG_OFF + b*N_ + t] = 1.0f / fmaxf((float)cnt, 1.0f);
  }
}

// ---------- k_anc: ancestor masks, independent of GRU chain ----------
__global__ void __launch_bounds__(64) k_anc(float* ws)
{
  int b = blockIdx.x, lane = threadIdx.x;
  uint32_t* wsu = (uint32_t*)ws;
  unsigned long long* ws64 = (unsigned long long*)ws;
  __shared__ unsigned long long AB[N_][4];
  if (lane < 4) AB[0][lane] = 0ULL;
  __syncthreads();
  const uint8_t* plb = ((const uint8_t*)&wsu[PL_OFF]) + (size_t)(b*N_)*N_;
  for (int t=1; t<N_; t++){
    if (lane < 16){
      int ip = lane>>2, w = lane&3;
      int pc = (int)wsu[PC_OFF + b*N_ + t];
      const uint8_t* pl = plb + (size_t)t*N_;
      unsigned long long acc = 0ULL;
      for (int i=ip;i<pc;i+=4) acc |= AB[pl[i]][w];
      acc |= __shfl_xor(acc, 4);
      acc |= __shfl_xor(acc, 8);
      if (ip == 0){
        ws64[AN64 + (size_t)(b*N_+t)*4 + w] = acc;
        AB[t][w] = acc | ws64[TG64 + (size_t)(b*N_+t)*4 + w];
      }
    }
    __syncthreads();
  }
}

// ---------- pass 1: 6 blocks/batch; W_ih row-partitioned, W_hh col-partitioned ----------
// ONE exchange per step (d-partials). h_prov computed fully locally by every block.
// Weights in LDS (deterministic residency). Block bx: b = bx&3, blk = bx>>2.
__global__ void __launch_bounds__(512, 1) k_pass1(const float* __restrict__ z,
    const float* __restrict__ Wih, const float* __restrict__ Whh,
    const float* __restrict__ bih_g, const float* __restrict__ bhh_g,
    float* ws)
{
  extern __shared__ __align__(16) char smem_[];
  float* L = (float*)smem_;
  uint32_t* Lu = (uint32_t*)smem_;

  int bx = blockIdx.x;
  int b   = bx & 3;
  int blk = bx >> 2;                // 0..5
  int tid = threadIdx.x;

  float* wsf = ws;
  uint32_t* wsu = (uint32_t*)ws;
  unsigned long long* ws64 = (unsigned long long*)ws;

  // ---- prologue: stage weights + tables into LDS ----
  // W_ih own rows (32 x 576) -> [k][c] pad 577
  for (int idx = tid; idx < OWNE*H3_; idx += 512){
    int k = idx / H3_, c = idx % H3_;
    L[L_WIH + k*577 + c] = Wih[(size_t)(OWNE*blk + k)*H3_ + c];
  }
  // W_hh own cols (192 x 96) -> [k][oc] pad 97
  for (int idx = tid; idx < H_*OWNC; idx += 512){
    int k = idx / OWNC, oc = idx % OWNC;
    int g = oc >> 5, jj = oc & 31;
    int gcol = g*H_ + OWNE*blk + jj;
    L[L_WHH + k*97 + oc] = Whh[(size_t)k*H3_ + gcol];
  }
  for (int c = tid; c < H3_; c += 512){
    L[L_Q + c]   = 0.0f;
    L[L_GZ + c]  = wsf[GZ_OFF + b*H3_ + c];
    L[L_BIH + c] = bih_g[c];
  }
  for (int e = tid; e < H_; e += 512) L[L_ZF + e] = z[b*H_ + e];
  for (int oc = tid; oc < OWNC; oc += 512){
    int g = oc >> 5, jj = oc & 31;
    L[L_BHH + oc] = bhh_g[g*H_ + OWNE*blk + jj];
  }
  for (int i = tid; i < N_; i += 512) Lu[L_SPC + i] = wsu[PC_OFF + b*N_ + i];
  if (tid < OWNE){
    float h0 = wsf[H0_OFF + b*H_ + OWNE*blk + tid];
    L[L_SSO + tid] = h0;
    wsf[SG_OFF + (size_t)(b*N_)*H_ + OWNE*blk + tid] = h0;   // S(0) own slice
  }
  __syncthreads();   // full drain once (prologue)

  // ---- per-thread setup ----
  const int c1 = tid;                         // col 1
  const int c2 = (tid < 64) ? tid + 512 : -1; // col 2
  int cm1 = c1 % H_;
  const int own1 = ((cm1 >> 5) == blk);
  const int oc1 = (c1/H_)*OWNE + (cm1 & 31);
  int own2 = 0, oc2 = 0;
  if (c2 >= 0){
    int cm2 = c2 % H_;
    own2 = ((cm2 >> 5) == blk);
    oc2 = (c2/H_)*OWNE + (cm2 & 31);
  }
  // publish slot bases (u64 index, par=0)
  unsigned long long* ownF1 = ws64 + FDP64 + (size_t)((b*NBLK+blk)*2)*H3_ + c1;
  unsigned long long* ownF2 = (c2>=0) ? ws64 + FDP64 + (size_t)((b*NBLK+blk)*2)*H3_ + c2 : (unsigned long long*)0;
  // foreign slot bases
  unsigned long long* pb1[5];
  unsigned long long* pb2[5];
  #pragma unroll
  for (int f=0; f<5; f++){
    int fb = (f < blk) ? f : f+1;
    pb1[f] = ws64 + FDP64 + (size_t)((b*NBLK+fb)*2)*H3_ + c1;
    pb2[f] = (c2>=0) ? ws64 + FDP64 + (size_t)((b*NBLK+fb)*2)*H3_ + c2 : (unsigned long long*)0;
  }
  float* Dglob = wsf + D_OFF + (size_t)((b*NBLK+blk)*N_)*OWNC;
  const uint8_t* plbase = ((const uint8_t*)&wsu[PL_OFF]) + (size_t)(b*N_)*N_;
  const int ocE = tid >> 2, kcE = tid & 3;    // phase-E mapping (tid<384)

  for (int t=1; t<N_; t++){
    const uint32_t tagH = (uint32_t)(t+1);
    const int parO = (t & 1) * H3_;           // parity offset in u64s
    // ---- A: d-partial over own 32 rows, cols c1 (,c2) ----
    float dp1 = 0.f, dp2 = 0.f;
    #pragma unroll
    for (int k=0; k<OWNE; k++){
      float sv = L[L_SSO + k];
      dp1 += sv * L[L_WIH + k*577 + c1];
      if (c2 >= 0) dp2 += sv * L[L_WIH + k*577 + c2];
    }
    {
      unsigned long long u1 = ((unsigned long long)tagH<<32) | (unsigned long long)__float_as_uint(dp1);
      st_fast_(ownF1 + parO, u1);
      st_mall_(ownF1 + parO + MOFF64, u1);
      if (c2 >= 0){
        unsigned long long u2 = ((unsigned long long)tagH<<32) | (unsigned long long)__float_as_uint(dp2);
        st_fast_(ownF2 + parO, u2);
        st_mall_(ownF2 + parO + MOFF64, u2);
      }
    }
    // ---- B: poll 5 foreign partials per col (batched nt + periodic MALL sweep) ----
    float sum1 = dp1, sum2 = dp2;
    unsigned got = (c2 >= 0) ? 0u : 0x3E0u;
    int it = 0;
    while (got != 0x3FFu){
      unsigned long long x0,x1,x2,x3,x4;
      ld_nt5_(pb1[0]+parO, pb1[1]+parO, pb1[2]+parO, pb1[3]+parO, pb1[4]+parO, x0,x1,x2,x3,x4);
      unsigned long long xa[5] = {x0,x1,x2,x3,x4};
      #pragma unroll
      for (int f=0; f<5; f++){
        if (!((got>>f)&1u) && (uint32_t)(xa[f]>>32) == tagH){
          sum1 += __uint_as_float((uint32_t)xa[f]); got |= 1u<<f;
        }
      }
      if (c2 >= 0){
        ld_nt5_(pb2[0]+parO, pb2[1]+parO, pb2[2]+parO, pb2[3]+parO, pb2[4]+parO, x0,x1,x2,x3,x4);
        unsigned long long xb[5] = {x0,x1,x2,x3,x4};
        #pragma unroll
        for (int f=0; f<5; f++){
          if (!((got>>(5+f))&1u) && (uint32_t)(xb[f]>>32) == tagH){
            sum2 += __uint_as_float((uint32_t)xb[f]); got |= 1u<<(5+f);
          }
        }
      }
      if (got == 0x3FFu) break;
      if ((it & 3) == 2){   // MALL sweep for stragglers (hang-proof fallback)
        #pragma unroll
        for (int f=0; f<5; f++){
          if (!((got>>f)&1u)){
            unsigned long long m = ld_mall_(pb1[f]+parO+MOFF64);
            if ((uint32_t)(m>>32) == tagH){ sum1 += __uint_as_float((uint32_t)m); got |= 1u<<f; }
          }
          if (c2 >= 0 && !((got>>(5+f))&1u)){
            unsigned long long m = ld_mall_(pb2[f]+parO+MOFF64);
            if ((uint32_t)(m>>32) == tagH){ sum2 += __uint_as_float((uint32_t)m); got |= 1u<<(5+f); }
          }
        }
      }
      if (++it > 12) __builtin_amdgcn_s_sleep(2);
    }
    // ---- C: q update (thread owns its cols), own-col D write, tf1 scalar ----
    L[L_Q + c1] += sum1;
    if (own1){ L[L_DOWN + oc1] = sum1; Dglob[(size_t)(t-1)*OWNC + oc1] = sum1; }
    if (c2 >= 0){
      L[L_Q + c2] += sum2;
      if (own2){ L[L_DOWN + oc2] = sum2; Dglob[(size_t)(t-1)*OWNC + oc2] = sum2; }
    }
    if (tid == 511){
      unsigned long long w1 = ws64[TG64 + (size_t)(b*N_+t)*4 + ((t-1)>>6)];
      L[L_STF] = (float)((w1 >> ((t-1)&63)) & 1ULL);
    }
    bar_();   // B1
    // ---- D: gates1 — full h_prov locally ----
    if (tid < H_){
      float invt = 1.0f/(float)t;
      int e = tid;
      float r = sigm_(L[L_Q+e]*invt       + L[L_BIH+e]       + L[L_GZ+e]);
      float u = sigm_(L[L_Q+H_+e]*invt    + L[L_BIH+H_+e]    + L[L_GZ+H_+e]);
      float n = tanh_(L[L_Q+2*H_+e]*invt  + L[L_BIH+2*H_+e]  + r*L[L_GZ+2*H_+e]);
      L[L_HP + e] = (1.0f-u)*n + u*L[L_ZF+e];
    }
    bar_();   // B2
    // ---- E: mv2 (y = hp@W_hh own cols) + parent gather; idle waves: HPG write ----
    if (tid < 384){
      float y = 0.f;
      const int k0 = kcE*48;
      #pragma unroll
      for (int k=0; k<48; k++) y += L[L_HP + k0 + k] * L[L_WHH + (k0+k)*97 + ocE];
      float ga = 0.f;
      {
        int pc = (int)Lu[L_SPC + t];
        const uint8_t* pl = plbase + (size_t)t*N_;
        for (int i=kcE; i<pc; i+=4){
          int p = pl[i];
          if (p == t-1) continue;
          ga += Dglob[(size_t)p*OWNC + ocE];
        }
      }
      y  += __shfl_xor(y, 1);  y  += __shfl_xor(y, 2);
      ga += __shfl_xor(ga, 1); ga += __shfl_xor(ga, 2);
      if (kcE == 0){ L[L_YGA + ocE] = y; L[L_GAA + ocE] = ga; }
    } else if (blk == 0){
      for (int e = tid-384; e < H_; e += 128)
        wsf[HPG_OFF + (size_t)(b*N_+t)*H_ + e] = L[L_HP + e];
    }
    bar_();   // B3
    // ---- F: gates2 — own 32 S elements ----
    if (tid < OWNE){
      int jj = tid;
      int pc = (int)Lu[L_SPC + t];
      float dgv = 1.0f / fmaxf((float)pc, 1.0f);
      float tf1 = L[L_STF];
      int gcb = OWNE*blk + jj;
      float gr = (L[L_GAA+jj]      + tf1*L[L_DOWN+jj])      * dgv + L[L_BIH + gcb];
      float gu = (L[L_GAA+32+jj]   + tf1*L[L_DOWN+32+jj])   * dgv + L[L_BIH + H_ + gcb];
      float gn = (L[L_GAA+64+jj]   + tf1*L[L_DOWN+64+jj])   * dgv + L[L_BIH + 2*H_ + gcb];
      float r2 = sigm_(gr + L[L_YGA+jj]    + L[L_BHH+jj]);
      float u2 = sigm_(gu + L[L_YGA+32+jj] + L[L_BHH+32+jj]);
      float n2 = tanh_(gn + r2*(L[L_YGA+64+jj] + L[L_BHH+64+jj]));
      float hn = (1.0f-u2)*n2 + u2*L[L_HP + gcb];
      L[L_SSO + jj] = hn;
      wsf[SG_OFF + (size_t)(b*N_+t)*H_ + gcb] = hn;
    }
    bar_();   // B4 — sSo/hp/yga safe for next step
  }
}

// ---------- pass 2a: G^T = (S@W1b)^T, C = Hprov@W1a + zc, NF = S@Wf + bf ----------
__global__ void k_p2a(const float* __restrict__ W1, const float* __restrict__ Wf,
    const float* __restrict__ bf, float* ws, float* out)
{
  int j = blockIdx.x, b = blockIdx.y, tid = threadIdx.x;
  __shared__ float srow[H_], hrow[H_];
  __shared__ float nfp[3][F_];
  srow[tid] = ws[SG_OFF + (size_t)(b*N_+j)*H_ + tid];
  hrow[tid] = ws[HPG_OFF + (size_t)(b*N_+j)*H_ + tid];   // garbage for j=0, C[0] unused
  __syncthreads();
  float accG = 0.f, accC = 0.f;
  for (int k=0;k<H_;k++){
    float sv = srow[k], hv = hrow[k];
    accG += sv * W1[(size_t)(H_+k)*H_ + tid];
    accC += hv * W1[(size_t)k*H_ + tid];
  }
  ws[G_OFF + ((size_t)b*H_ + tid)*N_ + j] = accG;    // transposed store
  ws[C_OFF + (size_t)(b*N_+j)*H_ + tid] = accC + ws[ZC_OFF + b*H_ + tid];
  int f = tid & 63, kp = tid >> 6;
  float a = 0.f;
  for (int i=0;i<64;i++){ int k = kp*64 + i; a += srow[k]*Wf[(size_t)k*F_ + f]; }
  nfp[kp][f] = a;
  __syncthreads();
  if (tid < F_) out[NF_OUT + (size_t)(b*N_+j)*F_ + tid] = nfp[0][tid]+nfp[1][tid]+nfp[2][tid] + bf[tid];
}

// ---------- pass 2b: log-likelihood, lane-per-candidate-parent ----------
__global__ void __launch_bounds__(256) k_p2b(const float* __restrict__ W2,
    const float* __restrict__ b2p, float* ws, float* out)
{
  int t = blockIdx.x + 1, b = blockIdx.y;
  int tid = threadIdx.x; int lane = tid & 63; int wv = tid >> 6;
  __shared__ float cv[H_], w2s[H_];
  __shared__ float wsum[4];
  unsigned long long* ws64 = (unsigned long long*)ws;
  if (tid < H_){
    cv[tid] = ws[C_OFF + (size_t)(b*N_+t)*H_ + tid];
    w2s[tid] = W2[tid];
  }
  __syncthreads();
  float acc = 0.f;
  if (tid < t){
    const float* GT = ws + G_OFF + (size_t)b*H_*N_;
    float a = 0.f;
    for (int k=0;k<H_;k++) a += fmaxf(cv[k] + GT[(size_t)k*N_ + tid], 0.f) * w2s[k];
    float logit = a + b2p[0];
    float pp = 1.0f/(1.0f+__expf(-logit));
    unsigned long long an = ws64[AN64 + (size_t)(b*N_+t)*4 + (tid>>6)];
    unsigned long long tg = ws64[TG64 + (size_t)(b*N_+t)*4 + (tid>>6)];
    float anc = (float)((an >> (tid&63)) & 1ULL);
    pp = pp * (1.0f - anc);
    pp = fminf(fmaxf(pp, 1e-6f), 1.0f - 1e-6f);
    int tgb = (int)((tg >> (tid&63)) & 1ULL);
    acc = tgb ? logf(pp) : log1pf(-pp);
  }
  #pragma unroll
  for (int m=32;m>=1;m>>=1) acc += __shfl_xor(acc, m);
  if (lane == 0) wsum[wv] = acc;
  __syncthreads();
  if (tid == 0) atomicAdd(out + LL_OUT, wsum[0]+wsum[1]+wsum[2]+wsum[3]);
}

extern "C" void kernel_launch(void* const* d_in, const int* in_sizes, int n_in,
                              void* d_out, int out_size, void* d_ws, size_t ws_size,
                              hipStream_t stream) {
  (void)in_sizes; (void)n_in; (void)out_size; (void)ws_size;
  const float* z     = (const float*)d_in[0];
  const float* tgt   = (const float*)d_in[1];
  const float* Winit = (const float*)d_in[2];
  const float* binit = (const float*)d_in[3];
  const float* Wih   = (const float*)d_in[4];
  const float* Whh   = (const float*)d_in[5];
  const float* bih   = (const float*)d_in[6];
  const float* bhh   = (const float*)d_in[7];
  const float* W1    = (const float*)d_in[8];
  const float* b1    = (const float*)d_in[9];
  const float* W2    = (const float*)d_in[10];
  const float* b2    = (const float*)d_in[11];
  const float* Wf    = (const float*)d_in[12];
  const float* bf    = (const float*)d_in[13];
  float* out = (float*)d_out;
  float* ws  = (float*)d_ws;

  static int smem_set = 0;
  if (!smem_set){
    hipFuncSetAttribute(reinterpret_cast<const void*>(&k_pass1),
                        hipFuncAttributeMaxDynamicSharedMemorySize, (int)SMEM_BYTES);
    smem_set = 1;
  }

  hipMemcpyAsync(d_out, d_in[1], (size_t)B_*N_*N_*sizeof(float), hipMemcpyDeviceToDevice, stream);

  k_pre1<<<dim3(N_+1, B_), dim3(192), 0, stream>>>(z, Winit, binit, W1, b1, Whh, bhh, tgt, ws, out);
  k_anc<<<dim3(B_), dim3(64), 0, stream>>>(ws);
  k_pass1<<<dim3(B_*NBLK), dim3(512), SMEM_BYTES, stream>>>(z, Wih, Whh, bih, bhh, ws);
  k_p2a<<<dim3(N_, B_), dim3(H_), 0, stream>>>(W1, Wf, bf, ws, out);
  k_p2b<<<dim3(N_-1, B_), dim3(256), 0, stream>>>(W2, b2, ws, out);
}

// Round 10
// 969.093 us; speedup vs baseline: 2.3261x; 2.3261x over previous
//
#include <hip/hip_runtime.h>
#include <stdint.h>

#define B_ 4
#define N_ 256
#define H_ 192
#define H3_ 576
#define F_ 64

// ---- workspace layout (32-bit words) ----
// HL/SL (MALL) and FHL/FSL (fast, XCD-L2) rows are 192 tagged u64:
// high32 = tag (t+1), low32 = fp32 bits. Tags 1..256; 0xAAAAAAAA poison never matches.
#define H0_OFF   0u
#define ZC_OFF   1024u
#define HL_OFF   2048u        // MALL h_prov rows [b][t][192] u64
#define SL_OFF   395264u      // MALL S rows
#define AN_OFF   788480u      // [b][t][4] u64 ancestor masks
#define TG_OFF   796672u      // [b][t][4] u64 target masks
#define PL_OFF   804864u      // parent lists (u8)
#define PC_OFF   870400u      // parent counts
#define DG_OFF   871424u      // 1/deg
#define D_OFF    872448u      // d-history [b][blk][node][192] f32 (own-block cols of S[node]@W_ih)
#define G_OFF    1462272u     // G^T: [b][k][N]  (post-pass only)
#define C_OFF    1658880u     // Hprov@W1a + zc  (post-pass only)
#define FHL_OFF  1855488u     // fast (XCD-L2) h_prov rows
#define FSL_OFF  2248704u     // fast (XCD-L2) S rows
#define XC_OFF   2641920u     // (unused)

#define AN64 (AN_OFF/2)
#define TG64 (TG_OFF/2)

#define NF_OUT 262144u
#define LL_OUT 327680u

__device__ __forceinline__ float sigm_(float x){ return 1.0f/(1.0f + __expf(-x)); }
__device__ __forceinline__ float tanh_(float x){
  float ax = fabsf(x);
  float e = __expf(-2.0f*ax);
  float t = (1.0f - e)/(1.0f + e);
  return x < 0.0f ? -t : t;
}

// MALL (agent/sc1) tagged ops — proven hang-proof publish/detect channel.
__device__ __forceinline__ void st_mall_(uint32_t* p, unsigned long long u){
  __hip_atomic_store((unsigned long long*)p, u, __ATOMIC_RELAXED, __HIP_MEMORY_SCOPE_AGENT);
}
__device__ __forceinline__ unsigned long long ld_mall_(const uint32_t* p){
  return __hip_atomic_load((const unsigned long long*)p, __ATOMIC_RELAXED, __HIP_MEMORY_SCOPE_AGENT);
}
// L2-executing returning atomic: add 0, sc0 (return old). Atomics execute AT the
// cache — a non-sc1 atomic executes at the XCD-shared L2 and returns the coherent
// L2 contents, bypassing the reader's L1 AND its own stale L2 line (the mechanism
// that defeated plain/sc0/nt spin loads in r2/r5/r7). Add-0 preserves the tag.
__device__ __forceinline__ unsigned long long ld_l2a_(uint32_t* p){
  unsigned long long old; unsigned long long zero = 0ULL;
  asm volatile("global_atomic_add_x2 %0, %1, %2, off sc0\n\t"
               "s_waitcnt vmcnt(0)"
               : "=&v"(old) : "v"((unsigned long long*)p), "v"(zero) : "memory");
  return old;
}
// dual publish: plain write-through store (own XCD L2) + sc1 store (MALL).
__device__ __forceinline__ void pub_(uint32_t* fp, uint32_t* mp, float v, uint32_t tag){
  unsigned long long u = ((unsigned long long)tag<<32) | (unsigned long long)__float_as_uint(v);
  __hip_atomic_store((unsigned long long*)fp, u, __ATOMIC_RELAXED, __HIP_MEMORY_SCOPE_WORKGROUP);
  st_mall_(mp, u);
}
// dual-spin poll: L2 atomic first (fast if publisher co-XCD), MALL fallback every
// iteration (hang-proof), s_sleep backoff (kills the r7 31ms spin-flood tail).
__device__ __forceinline__ float pollH_(uint32_t* fp, const uint32_t* mp, uint32_t tag){
  unsigned long long x; int it = 0;
  for(;;){
    x = ld_l2a_(fp);
    if ((uint32_t)(x>>32) != tag){
      unsigned long long m = ld_mall_(mp);
      if ((uint32_t)(m>>32) == tag) x = m;
    }
    if (__all((int)((uint32_t)(x>>32) == tag))) break;
    ++it;
    if (it > 64)      __builtin_amdgcn_s_sleep(8);
    else if (it > 24) __builtin_amdgcn_s_sleep(2);
  }
  return __uint_as_float((uint32_t)x);
}
// raw barrier: LDS ordering only — no vmcnt drain (keeps MALL acks off the barrier).
__device__ __forceinline__ void bar_(){
  asm volatile("s_waitcnt lgkmcnt(0)" ::: "memory");
  __builtin_amdgcn_s_barrier();
  asm volatile("" ::: "memory");
}

// ---------- pre1: (bx<N_): parent lists/bitmasks/deg | (bx==N_): h0, zc, ll=0 ----------
__global__ void __launch_bounds__(192) k_pre1(const float* __restrict__ z,
    const float* __restrict__ Winit, const float* __restrict__ binit,
    const float* __restrict__ W1, const float* __restrict__ b1,
    const float* __restrict__ tgt, float* ws, float* out)
{
  int bx = blockIdx.x, b = blockIdx.y, tid = threadIdx.x;
  if (bx == N_){
    __shared__ float zs[H_];
    zs[tid] = z[b*H_ + tid];
    __syncthreads();
    float a0=0.f, a1=0.f;
    for (int k=0;k<H_;k++){
      float zv = zs[k];
      a0 += zv * Winit[(size_t)k*H_ + tid];
      a1 += zv * W1[(size_t)(2*H_ + k)*H_ + tid];
    }
    ws[H0_OFF + b*H_ + tid] = tanh_(a0 + binit[tid]);
    ws[ZC_OFF + b*H_ + tid] = a1 + b1[tid];
    if (b==0 && tid==0) out[LL_OUT] = 0.0f;
    return;
  }
  if (tid >= 64) return;
  int t = bx, lane = tid;
  uint32_t* wsu = (uint32_t*)ws;
  unsigned long long* ws64 = (unsigned long long*)ws;
  const float* row = tgt + ((size_t)(b*N_) + t)*N_;
  uint8_t* pl = ((uint8_t*)&wsu[PL_OFF]) + (size_t)(b*N_ + t)*N_;
  int cnt = 0;
  #pragma unroll
  for (int m=0;m<4;m++){
    float v = row[m*64 + lane];
    bool p = (v != 0.0f);
    unsigned long long bw = __ballot(p);
    if (lane == 0) ws64[TG64 + (size_t)(b*N_+t)*4 + m] = bw;
    if (p){
      int pos = cnt + (int)__popcll(bw & ((1ULL<<lane)-1ULL));
      pl[pos] = (uint8_t)(m*64 + lane);
    }
    cnt += (int)__popcll(bw);
  }
  if (lane == 0){
    wsu[PC_OFF + b*N_ + t] = (uint32_t)cnt;
    ws[DG_OFF + b*N_ + t] = 1.0f / fmaxf((float)cnt, 1.0f);
  }
}

// ---------- pass 1: 3 blocks per batch, each owns 64 hidden elems (192 gate cols) ----------
// r7 schedule verbatim; only change: poll fast path = L2-executing returning atomic.
__global__ void __launch_bounds__(512, 2) k_pass1(const float* __restrict__ z,
    const float* __restrict__ Wih, const float* __restrict__ Whh,
    const float* __restrict__ bih_g, const float* __restrict__ bhh_g,
    float* ws)
{
  int bx = blockIdx.x;
  int b = bx & 7;
  if (b >= B_) return;
  int blk = bx >> 3;                 // 0..2, bx = b, 8+b, 16+b -> same XCD (round-robin)
  int tid = threadIdx.x;
  const int e  = tid >> 3;           // 0..63
  const int kc = tid & 7;            // 0..7
  const int E  = blk*64 + e;         // global hidden element

  float* wsf = ws;
  uint32_t* wsu = (uint32_t*)ws;
  unsigned long long* ws64 = (unsigned long long*)ws;

  __shared__ __align__(16) float sh[H_];     // h_prov(t), full vector
  __shared__ __align__(16) float ss[H_];     // S(t), full vector
  __shared__ float sDG[N_], sTF1[N_];
  __shared__ uint32_t sPC[N_];
  __shared__ unsigned long long sAB[N_][4];  // blk0 only

  // publish S(0) ASAP (tag 1)
  {
    float v = wsf[H0_OFF + b*H_ + E];
    if (kc == 0)
      pub_(&wsu[FSL_OFF + (unsigned)(b*N_)*384u + 2u*(unsigned)E],
           &wsu[SL_OFF  + (unsigned)(b*N_)*384u + 2u*(unsigned)E], v, 1u);
    if (kc == 1) ss[E] = v;
  }

  // ---- per-step scalar tables ----
  for (int i = tid; i < N_; i += 512){
    sDG[i] = wsf[DG_OFF + b*N_ + i];
    sPC[i] = wsu[PC_OFF + b*N_ + i];
    float f1 = 0.f;
    if (i >= 1){
      unsigned long long w1 = ws64[TG64 + (size_t)(b*N_+i)*4 + ((i-1)>>6)];
      f1 = (float)((w1 >> ((i-1)&63)) & 1ULL);
    }
    sTF1[i] = f1;
  }
  if (blk == 0 && tid >= 192 && tid < 196) sAB[0][tid-192] = 0ULL;

  // ---- weights: 3 gate cols x 24-k chunk ----
  float rwih[3][24], rwhh[3][24], rbih[3], rbhh[3], rghz[3];
  #pragma unroll
  for (int g=0; g<3; g++){
    int col = g*H_ + E;
    #pragma unroll
    for (int i=0;i<24;i++){
      rwih[g][i] = Wih[(size_t)(kc*24+i)*H3_ + col];
      rwhh[g][i] = Whh[(size_t)(kc*24+i)*H3_ + col];
    }
    rbih[g] = bih_g[col];
    rbhh[g] = bhh_g[col];
  }
  {
    // ghz = z@W_hh + b_hh (const across steps)
    float a0=0.f,a1=0.f,a2=0.f;
    #pragma unroll
    for (int i=0;i<24;i++){
      float zv = z[b*H_ + kc*24 + i];
      a0 += zv*rwhh[0][i]; a1 += zv*rwhh[1][i]; a2 += zv*rwhh[2][i];
    }
    #pragma unroll
    for (int m=1;m<8;m<<=1){
      a0 += __shfl_xor(a0,m); a1 += __shfl_xor(a1,m); a2 += __shfl_xor(a2,m);
    }
    rghz[0]=a0+rbhh[0]; rghz[1]=a1+rbhh[1]; rghz[2]=a2+rbhh[2];
  }
  float zreg = z[b*H_ + E];

  __syncthreads();   // full drain once: S(0) dual-publish committed
  // poll foreign S(0) into LDS
  if (tid < 128){
    int j = (tid < blk*64) ? tid : tid + 64;
    ss[j] = pollH_(&wsu[FSL_OFF + (unsigned)(b*N_)*384u + 2u*(unsigned)j],
                   &wsu[SL_OFF  + (unsigned)(b*N_)*384u + 2u*(unsigned)j], 1u);
  }
  __syncthreads();

  float q0=0.f, q1=0.f, q2=0.f;
  const uint8_t* plbase = ((const uint8_t*)&wsu[PL_OFF]) + (size_t)(b*N_)*N_;
  float* Dbase = wsf + D_OFF + (size_t)((b*3+blk)*N_)*H_;

  for (int t=1; t<N_; t++){
    const uint32_t tagH = (uint32_t)(t+1);
    // ---- mv1: d = S(t-1) @ W_ih (own 3 cols, k-chunk), butterfly over kc ----
    float d0=0.f,d1=0.f,d2=0.f;
    #pragma unroll
    for (int c=0;c<6;c++){
      float4 v4 = *(const float4*)&ss[kc*24 + c*4];
      float xx0=v4.x, xx1=v4.y, xx2=v4.z, xx3=v4.w;
      d0 += xx0*rwih[0][c*4+0]; d1 += xx0*rwih[1][c*4+0]; d2 += xx0*rwih[2][c*4+0];
      d0 += xx1*rwih[0][c*4+1]; d1 += xx1*rwih[1][c*4+1]; d2 += xx1*rwih[2][c*4+1];
      d0 += xx2*rwih[0][c*4+2]; d1 += xx2*rwih[1][c*4+2]; d2 += xx2*rwih[2][c*4+2];
      d0 += xx3*rwih[0][c*4+3]; d1 += xx3*rwih[1][c*4+3]; d2 += xx3*rwih[2][c*4+3];
    }
    #pragma unroll
    for (int m=1;m<8;m<<=1){
      d0 += __shfl_xor(d0,m); d1 += __shfl_xor(d1,m); d2 += __shfl_xor(d2,m);
    }
    q0 += d0; q1 += d1; q2 += d2;
    float invt = 1.0f/(float)t;
    // ---- gates1: h_prov ----
    float r = sigm_(q0*invt + rbih[0] + rghz[0]);
    float u = sigm_(q1*invt + rbih[1] + rghz[1]);
    float n = tanh_(q2*invt + rbih[2] + r*rghz[2]);
    float hp = (1.0f-u)*n + u*zreg;
    // publish h_prov + store own d row (node t-1)
    if (kc == 0){
      pub_(&wsu[FHL_OFF + (unsigned)(b*N_+t)*384u + 2u*(unsigned)E],
           &wsu[HL_OFF  + (unsigned)(b*N_+t)*384u + 2u*(unsigned)E], hp, tagH);
      float* Dr = Dbase + (size_t)(t-1)*H_;
      Dr[e] = d0; Dr[64+e] = d1; Dr[128+e] = d2;
    }
    if (kc == 1) sh[E] = hp;
    // ---- gather parent d (p <= t-2; p==t-1 handled via tf1*d in-reg) ----
    float ga0=0.f, ga1=0.f, ga2=0.f;
    {
      int pc = (int)sPC[t];
      const uint8_t* pl = plbase + (size_t)t*N_;
      for (int i=kc; i<pc; i+=8){
        int p = pl[i];
        if (p == t-1) continue;
        const float* Dp = Dbase + (size_t)p*H_;
        ga0 += Dp[e]; ga1 += Dp[64+e]; ga2 += Dp[128+e];
      }
    }
    #pragma unroll
    for (int m=1;m<8;m<<=1){
      ga0 += __shfl_xor(ga0,m); ga1 += __shfl_xor(ga1,m); ga2 += __shfl_xor(ga2,m);
    }
    // ---- phase-1 exchange: poll foreign h_prov; blk0 wave3 does ancestor row ----
    if (tid < 128){
      int j = (tid < blk*64) ? tid : tid + 64;
      sh[j] = pollH_(&wsu[FHL_OFF + (unsigned)(b*N_+t)*384u + 2u*(unsigned)j],
                     &wsu[HL_OFF  + (unsigned)(b*N_+t)*384u + 2u*(unsigned)j], tagH);
    } else if (blk == 0 && tid >= 192 && tid < 208){
      int lane16 = tid - 192;
      int ip = lane16 >> 2, w = lane16 & 3;
      int pc = (int)sPC[t];
      const uint8_t* pl = plbase + (size_t)t*N_;
      unsigned long long acc = 0ULL;
      for (int i=ip; i<pc; i+=4) acc |= sAB[pl[i]][w];
      acc |= __shfl_xor(acc, 4);
      acc |= __shfl_xor(acc, 8);
      if (ip == 0){
        ws64[AN64 + (size_t)(b*N_+t)*4 + w] = acc;
        sAB[t][w] = acc | ws64[TG64 + (size_t)(b*N_+t)*4 + w];
      }
    }
    bar_();   // B1 (lgkm only)
    // ---- mv2: gh2 = h_prov @ W_hh ----
    float y0=0.f,y1=0.f,y2=0.f;
    #pragma unroll
    for (int c=0;c<6;c++){
      float4 v4 = *(const float4*)&sh[kc*24 + c*4];
      float xx0=v4.x, xx1=v4.y, xx2=v4.z, xx3=v4.w;
      y0 += xx0*rwhh[0][c*4+0]; y1 += xx0*rwhh[1][c*4+0]; y2 += xx0*rwhh[2][c*4+0];
      y0 += xx1*rwhh[0][c*4+1]; y1 += xx1*rwhh[1][c*4+1]; y2 += xx1*rwhh[2][c*4+1];
      y0 += xx2*rwhh[0][c*4+2]; y1 += xx2*rwhh[1][c*4+2]; y2 += xx2*rwhh[2][c*4+2];
      y0 += xx3*rwhh[0][c*4+3]; y1 += xx3*rwhh[1][c*4+3]; y2 += xx3*rwhh[2][c*4+3];
    }
    #pragma unroll
    for (int m=1;m<8;m<<=1){
      y0 += __shfl_xor(y0,m); y1 += __shfl_xor(y1,m); y2 += __shfl_xor(y2,m);
    }
    // ---- gates2: S(t) ----
    float dginv = sDG[t], tf1 = sTF1[t];
    float gxa = (ga0 + tf1*d0)*dginv + rbih[0];
    float gxb = (ga1 + tf1*d1)*dginv + rbih[1];
    float gxc = (ga2 + tf1*d2)*dginv + rbih[2];
    float r2 = sigm_(gxa + y0 + rbhh[0]);
    float u2 = sigm_(gxb + y1 + rbhh[1]);
    float n2 = tanh_(gxc + r2*(y2 + rbhh[2]));
    float hn = (1.0f-u2)*n2 + u2*hp;
    if (kc == 0)
      pub_(&wsu[FSL_OFF + (unsigned)(b*N_+t)*384u + 2u*(unsigned)E],
           &wsu[SL_OFF  + (unsigned)(b*N_+t)*384u + 2u*(unsigned)E], hn, tagH);
    if (kc == 1) ss[E] = hn;
    // ---- phase-2 exchange: poll foreign S(t) ----
    if (tid < 128){
      int j = (tid < blk*64) ? tid : tid + 64;
      ss[j] = pollH_(&wsu[FSL_OFF + (unsigned)(b*N_+t)*384u + 2u*(unsigned)j],
                     &wsu[SL_OFF  + (unsigned)(b*N_+t)*384u + 2u*(unsigned)j], tagH);
    }
    bar_();   // B2 (lgkm only)
  }
}

// ---------- pass 2a: G^T = (S@W1b)^T, C = Hprov@W1a + zc, NF = S@Wf + bf ----------
__global__ void k_p2a(const float* __restrict__ W1, const float* __restrict__ Wf,
    const float* __restrict__ bf, float* ws, float* out)
{
  int j = blockIdx.x, b = blockIdx.y, tid = threadIdx.x;
  __shared__ float srow[H_], hrow[H_];
  __shared__ float nfp[3][F_];
  srow[tid] = ws[SL_OFF + (unsigned)(b*N_+j)*384u + 2u*tid];
  hrow[tid] = ws[HL_OFF + (unsigned)(b*N_+j)*384u + 2u*tid];   // garbage for j=0, C[0] unused
  __syncthreads();
  float accG = 0.f, accC = 0.f;
  for (int k=0;k<H_;k++){
    float sv = srow[k], hv = hrow[k];
    accG += sv * W1[(size_t)(H_+k)*H_ + tid];
    accC += hv * W1[(size_t)k*H_ + tid];
  }
  ws[G_OFF + ((size_t)b*H_ + tid)*N_ + j] = accG;    // transposed store
  ws[C_OFF + (size_t)(b*N_+j)*H_ + tid] = accC + ws[ZC_OFF + b*H_ + tid];
  int f = tid & 63, kp = tid >> 6;
  float a = 0.f;
  for (int i=0;i<64;i++){ int k = kp*64 + i; a += srow[k]*Wf[(size_t)k*F_ + f]; }
  nfp[kp][f] = a;
  __syncthreads();
  if (tid < F_) out[NF_OUT + (size_t)(b*N_+j)*F_ + tid] = nfp[0][tid]+nfp[1][tid]+nfp[2][tid] + bf[tid];
}

// ---------- pass 2b: log-likelihood, lane-per-candidate-parent ----------
__global__ void __launch_bounds__(256) k_p2b(const float* __restrict__ W2,
    const float* __restrict__ b2p, float* ws, float* out)
{
  int t = blockIdx.x + 1, b = blockIdx.y;
  int tid = threadIdx.x; int lane = tid & 63; int wv = tid >> 6;
  __shared__ float cv[H_], w2s[H_];
  __shared__ float wsum[4];
  unsigned long long* ws64 = (unsigned long long*)ws;
  if (tid < H_){
    cv[tid] = ws[C_OFF + (size_t)(b*N_+t)*H_ + tid];
    w2s[tid] = W2[tid];
  }
  __syncthreads();
  float acc = 0.f;
  if (tid < t){
    const float* GT = ws + G_OFF + (size_t)b*H_*N_;
    float a = 0.f;
    for (int k=0;k<H_;k++) a += fmaxf(cv[k] + GT[(size_t)k*N_ + tid], 0.f) * w2s[k];
    float logit = a + b2p[0];
    float pp = 1.0f/(1.0f+__expf(-logit));
    unsigned long long an = ws64[AN64 + (size_t)(b*N_+t)*4 + (tid>>6)];
    unsigned long long tg = ws64[TG64 + (size_t)(b*N_+t)*4 + (tid>>6)];
    float anc = (float)((an >> (tid&63)) & 1ULL);
    pp = pp * (1.0f - anc);
    pp = fminf(fmaxf(pp, 1e-6f), 1.0f - 1e-6f);
    int tgb = (int)((tg >> (tid&63)) & 1ULL);
    acc = tgb ? logf(pp) : log1pf(-pp);
  }
  #pragma unroll
  for (int m=32;m>=1;m>>=1) acc += __shfl_xor(acc, m);
  if (lane == 0) wsum[wv] = acc;
  __syncthreads();
  if (tid == 0) atomicAdd(out + LL_OUT, wsum[0]+wsum[1]+wsum[2]+wsum[3]);
}

extern "C" void kernel_launch(void* const* d_in, const int* in_sizes, int n_in,
                              void* d_out, int out_size, void* d_ws, size_t ws_size,
                              hipStream_t stream) {
  (void)in_sizes; (void)n_in; (void)out_size; (void)ws_size;
  const float* z     = (const float*)d_in[0];
  const float* tgt   = (const float*)d_in[1];
  const float* Winit = (const float*)d_in[2];
  const float* binit = (const float*)d_in[3];
  const float* Wih   = (const float*)d_in[4];
  const float* Whh   = (const float*)d_in[5];
  const float* bih   = (const float*)d_in[6];
  const float* bhh   = (const float*)d_in[7];
  const float* W1    = (const float*)d_in[8];
  const float* b1    = (const float*)d_in[9];
  const float* W2    = (const float*)d_in[10];
  const float* b2    = (const float*)d_in[11];
  const float* Wf    = (const float*)d_in[12];
  const float* bf    = (const float*)d_in[13];
  float* out = (float*)d_out;
  float* ws  = (float*)d_ws;

  (void)hipMemcpyAsync(d_out, d_in[1], (size_t)B_*N_*N_*sizeof(float), hipMemcpyDeviceToDevice, stream);

  k_pre1<<<dim3(N_+1, B_), dim3(192), 0, stream>>>(z, Winit, binit, W1, b1, tgt, ws, out);
  k_pass1<<<dim3(24), dim3(512), 0, stream>>>(z, Wih, Whh, bih, bhh, ws);
  k_p2a<<<dim3(N_, B_), dim3(H_), 0, stream>>>(W1, Wf, bf, ws, out);
  k_p2b<<<dim3(N_-1, B_), dim3(256), 0, stream>>>(W2, b2, ws, out);
}

// Round 11
// 929.732 us; speedup vs baseline: 2.4246x; 1.0423x over previous
//
#include <hip/hip_runtime.h>
#include <stdint.h>

#define B_ 4
#define N_ 256
#define H_ 192
#define H3_ 576
#define F_ 64

// ---- workspace layout (32-bit words) ----
// HL/SL (MALL) and FHL/FSL (fast, XCD-L2) rows are 192 tagged u64:
// high32 = tag (t+1), low32 = fp32 bits. Tags 1..256; 0xAAAAAAAA poison never matches.
#define H0_OFF   0u
#define ZC_OFF   1024u
#define HL_OFF   2048u        // MALL h_prov rows [b][t][192] u64
#define SL_OFF   395264u      // MALL S rows
#define AN_OFF   788480u      // [b][t][4] u64 ancestor masks
#define TG_OFF   796672u      // [b][t][4] u64 target masks
#define PL_OFF   804864u      // parent lists (u8)
#define PC_OFF   870400u      // parent counts
#define DG_OFF   871424u      // 1/deg
#define D_OFF    872448u      // d-history [b][blk][node][192] f32 (own-block cols of S[node]@W_ih)
#define G_OFF    1462272u     // G^T: [b][k][N]  (post-pass only)
#define C_OFF    1658880u     // Hprov@W1a + zc  (post-pass only)
#define FHL_OFF  1855488u     // fast (XCD-L2) h_prov rows
#define FSL_OFF  2248704u     // fast (XCD-L2) S rows
#define XC_OFF   2641920u     // (unused)

#define AN64 (AN_OFF/2)
#define TG64 (TG_OFF/2)

#define NF_OUT 262144u
#define LL_OUT 327680u

__device__ __forceinline__ float sigm_(float x){ return 1.0f/(1.0f + __expf(-x)); }
__device__ __forceinline__ float tanh_(float x){
  float ax = fabsf(x);
  float e = __expf(-2.0f*ax);
  float t = (1.0f - e)/(1.0f + e);
  return x < 0.0f ? -t : t;
}

// MALL (agent/sc1) tagged ops — proven hang-proof publish/detect channel.
__device__ __forceinline__ void st_mall_(uint32_t* p, unsigned long long u){
  __hip_atomic_store((unsigned long long*)p, u, __ATOMIC_RELAXED, __HIP_MEMORY_SCOPE_AGENT);
}
// dual publish: plain write-through store (own XCD L2) + sc1 store (MALL).
__device__ __forceinline__ void pub_(uint32_t* fp, uint32_t* mp, float v, uint32_t tag){
  unsigned long long u = ((unsigned long long)tag<<32) | (unsigned long long)__float_as_uint(v);
  __hip_atomic_store((unsigned long long*)fp, u, __ATOMIC_RELAXED, __HIP_MEMORY_SCOPE_WORKGROUP);
  st_mall_(mp, u);
}
// paired-poll: issue BOTH the nt (XCD-L2) load and the agent-scope (sc0 sc1, MALL)
// load back-to-back, wait vmcnt once. Iteration period = max(L2,MALL) RT instead of
// their sum (r7 serialized them: nt+drain, then MALL+drain). Prefer the fast copy.
// Hang-proof: the MALL copy is checked EVERY iteration and pub_ always writes it.
// s_sleep backoff (constant args) caps poll flood — the r7/r10 outlier mechanism.
__device__ __forceinline__ float pollH_(const uint32_t* fp, const uint32_t* mp, uint32_t tag){
  unsigned long long xf, xm; int it = 0;
  for(;;){
    asm volatile(
      "global_load_dwordx2 %0, %2, off nt\n\t"
      "global_load_dwordx2 %1, %3, off sc0 sc1\n\t"
      "s_waitcnt vmcnt(0)"
      : "=&v"(xf), "=&v"(xm)
      : "v"(fp), "v"(mp)
      : "memory");
    unsigned long long x = ((uint32_t)(xf>>32) == tag) ? xf : xm;
    if (__all((int)((uint32_t)(x>>32) == tag)))
      return __uint_as_float((uint32_t)x);
    ++it;
    if (it > 32)     __builtin_amdgcn_s_sleep(4);
    else if (it > 8) __builtin_amdgcn_s_sleep(1);
  }
}
// raw barrier: LDS ordering only — no vmcnt drain (keeps MALL acks off the barrier).
__device__ __forceinline__ void bar_(){
  asm volatile("s_waitcnt lgkmcnt(0)" ::: "memory");
  __builtin_amdgcn_s_barrier();
  asm volatile("" ::: "memory");
}

// ---------- pre1: (bx<N_): parent lists/bitmasks/deg | (bx==N_): h0, zc, ll=0 ----------
__global__ void __launch_bounds__(192) k_pre1(const float* __restrict__ z,
    const float* __restrict__ Winit, const float* __restrict__ binit,
    const float* __restrict__ W1, const float* __restrict__ b1,
    const float* __restrict__ tgt, float* ws, float* out)
{
  int bx = blockIdx.x, b = blockIdx.y, tid = threadIdx.x;
  if (bx == N_){
    __shared__ float zs[H_];
    zs[tid] = z[b*H_ + tid];
    __syncthreads();
    float a0=0.f, a1=0.f;
    for (int k=0;k<H_;k++){
      float zv = zs[k];
      a0 += zv * Winit[(size_t)k*H_ + tid];
      a1 += zv * W1[(size_t)(2*H_ + k)*H_ + tid];
    }
    ws[H0_OFF + b*H_ + tid] = tanh_(a0 + binit[tid]);
    ws[ZC_OFF + b*H_ + tid] = a1 + b1[tid];
    if (b==0 && tid==0) out[LL_OUT] = 0.0f;
    return;
  }
  if (tid >= 64) return;
  int t = bx, lane = tid;
  uint32_t* wsu = (uint32_t*)ws;
  unsigned long long* ws64 = (unsigned long long*)ws;
  const float* row = tgt + ((size_t)(b*N_) + t)*N_;
  uint8_t* pl = ((uint8_t*)&wsu[PL_OFF]) + (size_t)(b*N_ + t)*N_;
  int cnt = 0;
  #pragma unroll
  for (int m=0;m<4;m++){
    float v = row[m*64 + lane];
    bool p = (v != 0.0f);
    unsigned long long bw = __ballot(p);
    if (lane == 0) ws64[TG64 + (size_t)(b*N_+t)*4 + m] = bw;
    if (p){
      int pos = cnt + (int)__popcll(bw & ((1ULL<<lane)-1ULL));
      pl[pos] = (uint8_t)(m*64 + lane);
    }
    cnt += (int)__popcll(bw);
  }
  if (lane == 0){
    wsu[PC_OFF + b*N_ + t] = (uint32_t)cnt;
    ws[DG_OFF + b*N_ + t] = 1.0f / fmaxf((float)cnt, 1.0f);
  }
}

// ---------- pass 1: 3 blocks per batch, each owns 64 hidden elems (192 gate cols) ----------
// r7 schedule verbatim; only change: paired-issue poll (one vmcnt per iteration).
__global__ void __launch_bounds__(512, 2) k_pass1(const float* __restrict__ z,
    const float* __restrict__ Wih, const float* __restrict__ Whh,
    const float* __restrict__ bih_g, const float* __restrict__ bhh_g,
    float* ws)
{
  int bx = blockIdx.x;
  int b = bx & 7;
  if (b >= B_) return;
  int blk = bx >> 3;                 // 0..2, bx = b, 8+b, 16+b -> same XCD (round-robin)
  int tid = threadIdx.x;
  const int e  = tid >> 3;           // 0..63
  const int kc = tid & 7;            // 0..7
  const int E  = blk*64 + e;         // global hidden element

  float* wsf = ws;
  uint32_t* wsu = (uint32_t*)ws;
  unsigned long long* ws64 = (unsigned long long*)ws;

  __shared__ __align__(16) float sh[H_];     // h_prov(t), full vector
  __shared__ __align__(16) float ss[H_];     // S(t), full vector
  __shared__ float sDG[N_], sTF1[N_];
  __shared__ uint32_t sPC[N_];
  __shared__ unsigned long long sAB[N_][4];  // blk0 only

  // publish S(0) ASAP (tag 1)
  {
    float v = wsf[H0_OFF + b*H_ + E];
    if (kc == 0)
      pub_(&wsu[FSL_OFF + (unsigned)(b*N_)*384u + 2u*(unsigned)E],
           &wsu[SL_OFF  + (unsigned)(b*N_)*384u + 2u*(unsigned)E], v, 1u);
    if (kc == 1) ss[E] = v;
  }

  // ---- per-step scalar tables ----
  for (int i = tid; i < N_; i += 512){
    sDG[i] = wsf[DG_OFF + b*N_ + i];
    sPC[i] = wsu[PC_OFF + b*N_ + i];
    float f1 = 0.f;
    if (i >= 1){
      unsigned long long w1 = ws64[TG64 + (size_t)(b*N_+i)*4 + ((i-1)>>6)];
      f1 = (float)((w1 >> ((i-1)&63)) & 1ULL);
    }
    sTF1[i] = f1;
  }
  if (blk == 0 && tid >= 192 && tid < 196) sAB[0][tid-192] = 0ULL;

  // ---- weights: 3 gate cols x 24-k chunk ----
  float rwih[3][24], rwhh[3][24], rbih[3], rbhh[3], rghz[3];
  #pragma unroll
  for (int g=0; g<3; g++){
    int col = g*H_ + E;
    #pragma unroll
    for (int i=0;i<24;i++){
      rwih[g][i] = Wih[(size_t)(kc*24+i)*H3_ + col];
      rwhh[g][i] = Whh[(size_t)(kc*24+i)*H3_ + col];
    }
    rbih[g] = bih_g[col];
    rbhh[g] = bhh_g[col];
  }
  {
    // ghz = z@W_hh + b_hh (const across steps)
    float a0=0.f,a1=0.f,a2=0.f;
    #pragma unroll
    for (int i=0;i<24;i++){
      float zv = z[b*H_ + kc*24 + i];
      a0 += zv*rwhh[0][i]; a1 += zv*rwhh[1][i]; a2 += zv*rwhh[2][i];
    }
    #pragma unroll
    for (int m=1;m<8;m<<=1){
      a0 += __shfl_xor(a0,m); a1 += __shfl_xor(a1,m); a2 += __shfl_xor(a2,m);
    }
    rghz[0]=a0+rbhh[0]; rghz[1]=a1+rbhh[1]; rghz[2]=a2+rbhh[2];
  }
  float zreg = z[b*H_ + E];

  __syncthreads();   // full drain once: S(0) dual-publish committed
  // poll foreign S(0) into LDS
  if (tid < 128){
    int j = (tid < blk*64) ? tid : tid + 64;
    ss[j] = pollH_(&wsu[FSL_OFF + (unsigned)(b*N_)*384u + 2u*(unsigned)j],
                   &wsu[SL_OFF  + (unsigned)(b*N_)*384u + 2u*(unsigned)j], 1u);
  }
  __syncthreads();

  float q0=0.f, q1=0.f, q2=0.f;
  const uint8_t* plbase = ((const uint8_t*)&wsu[PL_OFF]) + (size_t)(b*N_)*N_;
  float* Dbase = wsf + D_OFF + (size_t)((b*3+blk)*N_)*H_;

  for (int t=1; t<N_; t++){
    const uint32_t tagH = (uint32_t)(t+1);
    // ---- mv1: d = S(t-1) @ W_ih (own 3 cols, k-chunk), butterfly over kc ----
    float d0=0.f,d1=0.f,d2=0.f;
    #pragma unroll
    for (int c=0;c<6;c++){
      float4 v4 = *(const float4*)&ss[kc*24 + c*4];
      float xx0=v4.x, xx1=v4.y, xx2=v4.z, xx3=v4.w;
      d0 += xx0*rwih[0][c*4+0]; d1 += xx0*rwih[1][c*4+0]; d2 += xx0*rwih[2][c*4+0];
      d0 += xx1*rwih[0][c*4+1]; d1 += xx1*rwih[1][c*4+1]; d2 += xx1*rwih[2][c*4+1];
      d0 += xx2*rwih[0][c*4+2]; d1 += xx2*rwih[1][c*4+2]; d2 += xx2*rwih[2][c*4+2];
      d0 += xx3*rwih[0][c*4+3]; d1 += xx3*rwih[1][c*4+3]; d2 += xx3*rwih[2][c*4+3];
    }
    #pragma unroll
    for (int m=1;m<8;m<<=1){
      d0 += __shfl_xor(d0,m); d1 += __shfl_xor(d1,m); d2 += __shfl_xor(d2,m);
    }
    q0 += d0; q1 += d1; q2 += d2;
    float invt = 1.0f/(float)t;
    // ---- gates1: h_prov ----
    float r = sigm_(q0*invt + rbih[0] + rghz[0]);
    float u = sigm_(q1*invt + rbih[1] + rghz[1]);
    float n = tanh_(q2*invt + rbih[2] + r*rghz[2]);
    float hp = (1.0f-u)*n + u*zreg;
    // publish h_prov + store own d row (node t-1)
    if (kc == 0){
      pub_(&wsu[FHL_OFF + (unsigned)(b*N_+t)*384u + 2u*(unsigned)E],
           &wsu[HL_OFF  + (unsigned)(b*N_+t)*384u + 2u*(unsigned)E], hp, tagH);
      float* Dr = Dbase + (size_t)(t-1)*H_;
      Dr[e] = d0; Dr[64+e] = d1; Dr[128+e] = d2;
    }
    if (kc == 1) sh[E] = hp;
    // ---- gather parent d (p <= t-2; p==t-1 handled via tf1*d in-reg) ----
    float ga0=0.f, ga1=0.f, ga2=0.f;
    {
      int pc = (int)sPC[t];
      const uint8_t* pl = plbase + (size_t)t*N_;
      for (int i=kc; i<pc; i+=8){
        int p = pl[i];
        if (p == t-1) continue;
        const float* Dp = Dbase + (size_t)p*H_;
        ga0 += Dp[e]; ga1 += Dp[64+e]; ga2 += Dp[128+e];
      }
    }
    #pragma unroll
    for (int m=1;m<8;m<<=1){
      ga0 += __shfl_xor(ga0,m); ga1 += __shfl_xor(ga1,m); ga2 += __shfl_xor(ga2,m);
    }
    // ---- phase-1 exchange: poll foreign h_prov; blk0 wave3 does ancestor row ----
    if (tid < 128){
      int j = (tid < blk*64) ? tid : tid + 64;
      sh[j] = pollH_(&wsu[FHL_OFF + (unsigned)(b*N_+t)*384u + 2u*(unsigned)j],
                     &wsu[HL_OFF  + (unsigned)(b*N_+t)*384u + 2u*(unsigned)j], tagH);
    } else if (blk == 0 && tid >= 192 && tid < 208){
      int lane16 = tid - 192;
      int ip = lane16 >> 2, w = lane16 & 3;
      int pc = (int)sPC[t];
      const uint8_t* pl = plbase + (size_t)t*N_;
      unsigned long long acc = 0ULL;
      for (int i=ip; i<pc; i+=4) acc |= sAB[pl[i]][w];
      acc |= __shfl_xor(acc, 4);
      acc |= __shfl_xor(acc, 8);
      if (ip == 0){
        ws64[AN64 + (size_t)(b*N_+t)*4 + w] = acc;
        sAB[t][w] = acc | ws64[TG64 + (size_t)(b*N_+t)*4 + w];
      }
    }
    bar_();   // B1 (lgkm only)
    // ---- mv2: gh2 = h_prov @ W_hh ----
    float y0=0.f,y1=0.f,y2=0.f;
    #pragma unroll
    for (int c=0;c<6;c++){
      float4 v4 = *(const float4*)&sh[kc*24 + c*4];
      float xx0=v4.x, xx1=v4.y, xx2=v4.z, xx3=v4.w;
      y0 += xx0*rwhh[0][c*4+0]; y1 += xx0*rwhh[1][c*4+0]; y2 += xx0*rwhh[2][c*4+0];
      y0 += xx1*rwhh[0][c*4+1]; y1 += xx1*rwhh[1][c*4+1]; y2 += xx1*rwhh[2][c*4+1];
      y0 += xx2*rwhh[0][c*4+2]; y1 += xx2*rwhh[1][c*4+2]; y2 += xx2*rwhh[2][c*4+2];
      y0 += xx3*rwhh[0][c*4+3]; y1 += xx3*rwhh[1][c*4+3]; y2 += xx3*rwhh[2][c*4+3];
    }
    #pragma unroll
    for (int m=1;m<8;m<<=1){
      y0 += __shfl_xor(y0,m); y1 += __shfl_xor(y1,m); y2 += __shfl_xor(y2,m);
    }
    // ---- gates2: S(t) ----
    float dginv = sDG[t], tf1 = sTF1[t];
    float gxa = (ga0 + tf1*d0)*dginv + rbih[0];
    float gxb = (ga1 + tf1*d1)*dginv + rbih[1];
    float gxc = (ga2 + tf1*d2)*dginv + rbih[2];
    float r2 = sigm_(gxa + y0 + rbhh[0]);
    float u2 = sigm_(gxb + y1 + rbhh[1]);
    float n2 = tanh_(gxc + r2*(y2 + rbhh[2]));
    float hn = (1.0f-u2)*n2 + u2*hp;
    if (kc == 0)
      pub_(&wsu[FSL_OFF + (unsigned)(b*N_+t)*384u + 2u*(unsigned)E],
           &wsu[SL_OFF  + (unsigned)(b*N_+t)*384u + 2u*(unsigned)E], hn, tagH);
    if (kc == 1) ss[E] = hn;
    // ---- phase-2 exchange: poll foreign S(t) ----
    if (tid < 128){
      int j = (tid < blk*64) ? tid : tid + 64;
      ss[j] = pollH_(&wsu[FSL_OFF + (unsigned)(b*N_+t)*384u + 2u*(unsigned)j],
                     &wsu[SL_OFF  + (unsigned)(b*N_+t)*384u + 2u*(unsigned)j], tagH);
    }
    bar_();   // B2 (lgkm only)
  }
}

// ---------- pass 2a: G^T = (S@W1b)^T, C = Hprov@W1a + zc, NF = S@Wf + bf ----------
__global__ void k_p2a(const float* __restrict__ W1, const float* __restrict__ Wf,
    const float* __restrict__ bf, float* ws, float* out)
{
  int j = blockIdx.x, b = blockIdx.y, tid = threadIdx.x;
  __shared__ float srow[H_], hrow[H_];
  __shared__ float nfp[3][F_];
  srow[tid] = ws[SL_OFF + (unsigned)(b*N_+j)*384u + 2u*tid];
  hrow[tid] = ws[HL_OFF + (unsigned)(b*N_+j)*384u + 2u*tid];   // garbage for j=0, C[0] unused
  __syncthreads();
  float accG = 0.f, accC = 0.f;
  for (int k=0;k<H_;k++){
    float sv = srow[k], hv = hrow[k];
    accG += sv * W1[(size_t)(H_+k)*H_ + tid];
    accC += hv * W1[(size_t)k*H_ + tid];
  }
  ws[G_OFF + ((size_t)b*H_ + tid)*N_ + j] = accG;    // transposed store
  ws[C_OFF + (size_t)(b*N_+j)*H_ + tid] = accC + ws[ZC_OFF + b*H_ + tid];
  int f = tid & 63, kp = tid >> 6;
  float a = 0.f;
  for (int i=0;i<64;i++){ int k = kp*64 + i; a += srow[k]*Wf[(size_t)k*F_ + f]; }
  nfp[kp][f] = a;
  __syncthreads();
  if (tid < F_) out[NF_OUT + (size_t)(b*N_+j)*F_ + tid] = nfp[0][tid]+nfp[1][tid]+nfp[2][tid] + bf[tid];
}

// ---------- pass 2b: log-likelihood, lane-per-candidate-parent ----------
__global__ void __launch_bounds__(256) k_p2b(const float* __restrict__ W2,
    const float* __restrict__ b2p, float* ws, float* out)
{
  int t = blockIdx.x + 1, b = blockIdx.y;
  int tid = threadIdx.x; int lane = tid & 63; int wv = tid >> 6;
  __shared__ float cv[H_], w2s[H_];
  __shared__ float wsum[4];
  unsigned long long* ws64 = (unsigned long long*)ws;
  if (tid < H_){
    cv[tid] = ws[C_OFF + (size_t)(b*N_+t)*H_ + tid];
    w2s[tid] = W2[tid];
  }
  __syncthreads();
  float acc = 0.f;
  if (tid < t){
    const float* GT = ws + G_OFF + (size_t)b*H_*N_;
    float a = 0.f;
    for (int k=0;k<H_;k++) a += fmaxf(cv[k] + GT[(size_t)k*N_ + tid], 0.f) * w2s[k];
    float logit = a + b2p[0];
    float pp = 1.0f/(1.0f+__expf(-logit));
    unsigned long long an = ws64[AN64 + (size_t)(b*N_+t)*4 + (tid>>6)];
    unsigned long long tg = ws64[TG64 + (size_t)(b*N_+t)*4 + (tid>>6)];
    float anc = (float)((an >> (tid&63)) & 1ULL);
    pp = pp * (1.0f - anc);
    pp = fminf(fmaxf(pp, 1e-6f), 1.0f - 1e-6f);
    int tgb = (int)((tg >> (tid&63)) & 1ULL);
    acc = tgb ? logf(pp) : log1pf(-pp);
  }
  #pragma unroll
  for (int m=32;m>=1;m>>=1) acc += __shfl_xor(acc, m);
  if (lane == 0) wsum[wv] = acc;
  __syncthreads();
  if (tid == 0) atomicAdd(out + LL_OUT, wsum[0]+wsum[1]+wsum[2]+wsum[3]);
}

extern "C" void kernel_launch(void* const* d_in, const int* in_sizes, int n_in,
                              void* d_out, int out_size, void* d_ws, size_t ws_size,
                              hipStream_t stream) {
  (void)in_sizes; (void)n_in; (void)out_size; (void)ws_size;
  const float* z     = (const float*)d_in[0];
  const float* tgt   = (const float*)d_in[1];
  const float* Winit = (const float*)d_in[2];
  const float* binit = (const float*)d_in[3];
  const float* Wih   = (const float*)d_in[4];
  const float* Whh   = (const float*)d_in[5];
  const float* bih   = (const float*)d_in[6];
  const float* bhh   = (const float*)d_in[7];
  const float* W1    = (const float*)d_in[8];
  const float* b1    = (const float*)d_in[9];
  const float* W2    = (const float*)d_in[10];
  const float* b2    = (const float*)d_in[11];
  const float* Wf    = (const float*)d_in[12];
  const float* bf    = (const float*)d_in[13];
  float* out = (float*)d_out;
  float* ws  = (float*)d_ws;

  (void)hipMemcpyAsync(d_out, d_in[1], (size_t)B_*N_*N_*sizeof(float), hipMemcpyDeviceToDevice, stream);

  k_pre1<<<dim3(N_+1, B_), dim3(192), 0, stream>>>(z, Winit, binit, W1, b1, tgt, ws, out);
  k_pass1<<<dim3(24), dim3(512), 0, stream>>>(z, Wih, Whh, bih, bhh, ws);
  k_p2a<<<dim3(N_, B_), dim3(H_), 0, stream>>>(W1, Wf, bf, ws, out);
  k_p2b<<<dim3(N_-1, B_), dim3(256), 0, stream>>>(W2, b2, ws, out);
}